// Round 4
// baseline (452.152 us; speedup 1.0000x reference)
//
#include <hip/hip_runtime.h>

#define BINS 2048

// ---- order-preserving float <-> uint encoding for atomic min/max ----
__device__ __forceinline__ unsigned encf(float f) {
    unsigned u = __float_as_uint(f);
    return (u & 0x80000000u) ? ~u : (u | 0x80000000u);
}
__device__ __forceinline__ float decf(unsigned k) {
    unsigned u = (k & 0x80000000u) ? (k ^ 0x80000000u) : ~k;
    return __uint_as_float(u);
}

// ws layout (uint32): [0]=enc_min, [1]=enc_max, [2 .. 2+BINS) = hist counts
__global__ void k_init(unsigned* __restrict__ ws) {
    int i = blockIdx.x * blockDim.x + threadIdx.x;
    if (i < BINS) ws[2 + i] = 0u;
    if (i == 0) { ws[0] = 0xFFFFFFFFu; ws[1] = 0u; }
}

__global__ void k_minmax(const float4* __restrict__ x, int n4, int ntail,
                         unsigned* __restrict__ ws) {
    float vmin = __uint_as_float(0x7F800000u);   // +inf
    float vmax = __uint_as_float(0xFF800000u);   // -inf
    int tid = blockIdx.x * blockDim.x + threadIdx.x;
    int stride = gridDim.x * blockDim.x;
    for (int i = tid; i < n4; i += stride) {
        float4 v = x[i];
        vmin = fminf(vmin, fminf(fminf(v.x, v.y), fminf(v.z, v.w)));
        vmax = fmaxf(vmax, fmaxf(fmaxf(v.x, v.y), fmaxf(v.z, v.w)));
    }
    if (tid < ntail) {   // scalar tail (n not divisible by 4)
        float f = ((const float*)x)[4 * n4 + tid];
        vmin = fminf(vmin, f); vmax = fmaxf(vmax, f);
    }
    #pragma unroll
    for (int o = 32; o > 0; o >>= 1) {
        vmin = fminf(vmin, __shfl_xor(vmin, o, 64));
        vmax = fmaxf(vmax, __shfl_xor(vmax, o, 64));
    }
    __shared__ float smin[8], smax[8];
    int wid = threadIdx.x >> 6;
    if ((threadIdx.x & 63) == 0) { smin[wid] = vmin; smax[wid] = vmax; }
    __syncthreads();
    if (threadIdx.x == 0) {
        int nw = (int)(blockDim.x >> 6);
        float bmin = smin[0], bmax = smax[0];
        for (int w = 1; w < nw; ++w) { bmin = fminf(bmin, smin[w]); bmax = fmaxf(bmax, smax[w]); }
        atomicMin(&ws[0], encf(bmin));
        atomicMax(&ws[1], encf(bmax));
    }
}

__global__ void k_hist(const float4* __restrict__ x, int n4, int ntail,
                       const float* __restrict__ rmin, const float* __restrict__ rmax,
                       unsigned* __restrict__ ws) {
    __shared__ unsigned lh[BINS];
    for (int j = threadIdx.x; j < BINS; j += blockDim.x) lh[j] = 0u;
    __syncthreads();

    float new_min = fminf(decf(ws[0]), rmin[0]);
    float new_max = fmaxf(decf(ws[1]), rmax[0]);
    float w = __fdiv_rn(__fsub_rn(new_max, new_min), (float)BINS);
    float safe_w = (w > 0.0f) ? w : 1.0f;

    int tid = blockIdx.x * blockDim.x + threadIdx.x;
    int stride = gridDim.x * blockDim.x;
    for (int i = tid; i < n4; i += stride) {
        float4 v = x[i];
        int b0 = (int)floorf(__fdiv_rn(__fsub_rn(v.x, new_min), safe_w));
        int b1 = (int)floorf(__fdiv_rn(__fsub_rn(v.y, new_min), safe_w));
        int b2 = (int)floorf(__fdiv_rn(__fsub_rn(v.z, new_min), safe_w));
        int b3 = (int)floorf(__fdiv_rn(__fsub_rn(v.w, new_min), safe_w));
        atomicAdd(&lh[min(max(b0, 0), BINS - 1)], 1u);
        atomicAdd(&lh[min(max(b1, 0), BINS - 1)], 1u);
        atomicAdd(&lh[min(max(b2, 0), BINS - 1)], 1u);
        atomicAdd(&lh[min(max(b3, 0), BINS - 1)], 1u);
    }
    if (tid < ntail) {
        float f = ((const float*)x)[4 * n4 + tid];
        int b = (int)floorf(__fdiv_rn(__fsub_rn(f, new_min), safe_w));
        atomicAdd(&lh[min(max(b, 0), BINS - 1)], 1u);
    }
    __syncthreads();
    for (int j = threadIdx.x; j < BINS; j += blockDim.x) {
        unsigned c = lh[j];
        if (c) atomicAdd(&ws[2 + j], c);
    }
}

// Single block: phase 1 writes counts+min/max to out, phase 2 folds
// running_hist into the new grid (reference _combine_histograms, exact fp op
// order). __syncthreads between phases keeps the atomicAdd ordering safe.
__global__ __launch_bounds__(1024) void k_finalize(
        const float* __restrict__ rhist,
        const float* __restrict__ rminp, const float* __restrict__ rmaxp,
        const unsigned* __restrict__ ws, float* __restrict__ out) {
    float r_min = rminp[0], r_max = rmaxp[0];
    float new_min = fminf(decf(ws[0]), r_min);
    float new_max = fmaxf(decf(ws[1]), r_max);

    // phase 1: counts -> out, plus the two scalars
    for (int i = threadIdx.x; i < BINS; i += blockDim.x) out[i] = (float)ws[2 + i];
    if (threadIdx.x == 0) { out[BINS] = new_min; out[BINS + 1] = new_max; }
    __syncthreads();

    // phase 2: merge running hist
    float w = __fdiv_rn(__fsub_rn(new_max, new_min), (float)BINS);   // dst_bin_width
    float safe_w = (w > 0.0f) ? w : 1.0f;
    float sbw = __fdiv_rn(__fsub_rn(r_max, r_min), (float)BINS);     // src_bin_width
    float safe_sw = (sbw > 0.0f) ? sbw : 1.0f;
    bool degenerate = (sbw == 0.0f) || (w == 0.0f);

    for (int i = threadIdx.x; i < BINS; i += blockDim.x) {
        float fi = (float)i;
        float src_begin = __fadd_rn(r_min, __fmul_rn(sbw, fi));
        float src_end   = __fadd_rn(src_begin, sbw);
        int db  = min(max((int)floorf(__fdiv_rn(__fsub_rn(src_begin, new_min), safe_w)), 0), BINS - 1);
        int db2 = min(max((int)floorf(__fdiv_rn(__fsub_rn(src_end,   new_min), safe_w)), 0), BINS - 1);
        float dst_bin_end = __fadd_rn(new_min, __fmul_rn(w, (float)(db + 1)));
        float cnt = rhist[i];
        // jnp.round is round-half-to-even -> rintf
        float frac = fminf(rintf(__fmul_rn(__fdiv_rn(__fsub_rn(dst_bin_end, src_begin), safe_sw), cnt)), cnt);
        float dc = degenerate ? cnt : frac;
        atomicAdd(&out[db],  dc);
        atomicAdd(&out[db2], cnt - dc);
    }
}

extern "C" void kernel_launch(void* const* d_in, const int* in_sizes, int n_in,
                              void* d_out, int out_size, void* d_ws, size_t ws_size,
                              hipStream_t stream) {
    const float* x     = (const float*)d_in[0];
    const float* rhist = (const float*)d_in[1];
    const float* rmin  = (const float*)d_in[2];
    const float* rmax  = (const float*)d_in[3];
    float* out   = (float*)d_out;
    unsigned* ws = (unsigned*)d_ws;

    int n = in_sizes[0];
    int n4 = n >> 2;
    int ntail = n - (n4 << 2);

    k_init<<<(BINS + 255) / 256, 256, 0, stream>>>(ws);
    k_minmax<<<2048, 256, 0, stream>>>((const float4*)x, n4, ntail, ws);
    k_hist<<<1024, 256, 0, stream>>>((const float4*)x, n4, ntail, rmin, rmax, ws);
    k_finalize<<<1, 1024, 0, stream>>>(rhist, rmin, rmax, ws, out);
}